// Round 6
// baseline (4152.902 us; speedup 1.0000x reference)
//
#include <hip/hip_runtime.h>

#define B_   64
#define T_   512
#define HID_ 512
#define H_   256
#define G4   1024
#define N2   2048
#define M_   (B_*T_)
#define NL_  9

typedef short short8 __attribute__((ext_vector_type(8)));
typedef float f32x4 __attribute__((ext_vector_type(4)));
typedef _Float16 f16x2 __attribute__((ext_vector_type(2)));

__device__ inline float bf2f(unsigned short u) {
  unsigned int x = ((unsigned int)u) << 16;
  return __builtin_bit_cast(float, x);
}
__device__ inline unsigned short f2bf(float f) {
  unsigned int u = __builtin_bit_cast(unsigned int, f);
  return (unsigned short)((u + 0x7fffu + ((u >> 16) & 1u)) >> 16);
}
__device__ inline unsigned short f2h(float f) {
  _Float16 h = (_Float16)f;
  return __builtin_bit_cast(unsigned short, h);
}
__device__ inline float fdot2(unsigned int w, unsigned int h, float acc) {
#if __has_builtin(__builtin_amdgcn_fdot2)
  return __builtin_amdgcn_fdot2(__builtin_bit_cast(f16x2, w),
                                __builtin_bit_cast(f16x2, h), acc, false);
#else
  f16x2 a = __builtin_bit_cast(f16x2, w), b = __builtin_bit_cast(f16x2, h);
  return acc + (float)a[0]*(float)b[0] + (float)a[1]*(float)b[1];
#endif
}
__device__ inline float sigm(float x)     { return 1.f / (1.f + __expf(-x)); }
__device__ inline float tanhfast(float x) { return 1.f - 2.f / (__expf(2.f*x) + 1.f); }

// ---------------- prep kernels ----------------
__global__ void k_cast_bf16(const float* __restrict__ src, unsigned short* __restrict__ dst, int n) {
  int i = blockIdx.x*256 + threadIdx.x;
  if (i < n) dst[i] = f2bf(src[i]);
}

// w_hh (2,2,1024,256) fp32 -> fp16 pairs:
//   k<192  -> wreg[((ld*1024+col)*96) + kp]      (per-col contiguous, 384 B/col)
//   k>=192 -> wlds[((ld*8+blk)*1024+col)*4 + q]
__global__ void k_pack_whh(const float* __restrict__ whh, unsigned int* __restrict__ wreg,
                           unsigned int* __restrict__ wlds) {
  int idx = blockIdx.x*256 + threadIdx.x;           // 2*2*1024*128 = 524288
  int kp  = idx & 127;
  int col = (idx >> 7) & 1023;
  int ld  = idx >> 17;                              // l*2+d
  const float* src = whh + ((size_t)ld*1024 + col)*256 + kp*2;
  unsigned int pack = (unsigned int)f2h(src[0]) | ((unsigned int)f2h(src[1]) << 16);
  if (kp < 96) {
    wreg[((size_t)ld*1024 + col)*96 + kp] = pack;
  } else {
    int kq = kp - 96, blk = kq >> 2, q = kq & 3;
    wlds[(((size_t)ld*8 + blk)*1024 + col)*4 + q] = pack;
  }
}

__global__ void k_bias_sum(const float* __restrict__ bi, const float* __restrict__ bh,
                           float* __restrict__ bs) {
  int i = blockIdx.x*256 + threadIdx.x;
  if (i < 4096) bs[i] = bi[i] + bh[i];
}

__global__ void k_cls_pad(const float* __restrict__ w, unsigned short* __restrict__ dst) {
  int i = blockIdx.x*256 + threadIdx.x;             // 16*512
  if (i < 16*512) {
    int n = i >> 9, k = i & 511;
    dst[i] = (n < NL_) ? f2bf(w[n*512 + k]) : (unsigned short)0;
  }
}

__global__ void k_embed(const int* __restrict__ ids, const float* __restrict__ emb,
                        unsigned short* __restrict__ x0) {
  int idx = blockIdx.x*256 + threadIdx.x;           // M_*128
  int m  = idx >> 7;
  int e4 = (idx & 127) << 2;
  int id = ids[m];
  float4 v = *(const float4*)(emb + (size_t)id*HID_ + e4);
  unsigned short* dst = x0 + (size_t)m*HID_ + e4;
  dst[0]=f2bf(v.x); dst[1]=f2bf(v.y); dst[2]=f2bf(v.z); dst[3]=f2bf(v.w);
}

// ---------------- input-projection GEMM (bf16 MFMA, fragments direct from L2) ----------------
// C[m][n] = sum_k A[m][k]*Bt[n][k] + bias[n],  M=32768 N=2048 K=512, out bf16
__global__ __launch_bounds__(256) void k_gemm_inproj(const unsigned short* __restrict__ A,
    const unsigned short* __restrict__ Bt, const float* __restrict__ bias,
    unsigned short* __restrict__ C) {
  int lane = threadIdx.x & 63, wave = threadIdx.x >> 6;
  int n0 = blockIdx.x * 64;
  int m0 = blockIdx.y * 64 + wave * 16;
  int r = lane & 15, kg = lane >> 4;
  const short8* Ap = (const short8*)(A + (size_t)(m0 + r)*512 + kg*8);
  const short8* Bp = (const short8*)(Bt + (size_t)(n0 + r)*512 + kg*8);
  f32x4 acc0 = {0,0,0,0}, acc1 = {0,0,0,0}, acc2 = {0,0,0,0}, acc3 = {0,0,0,0};
  #pragma unroll
  for (int kb = 0; kb < 16; kb++) {
    short8 a  = Ap[kb*4];
    short8 b0 = Bp[kb*4];
    short8 b1 = Bp[kb*4 + 1024];     // +16 rows (16*512/8)
    short8 b2 = Bp[kb*4 + 2048];
    short8 b3 = Bp[kb*4 + 3072];
    acc0 = __builtin_amdgcn_mfma_f32_16x16x32_bf16(a, b0, acc0, 0, 0, 0);
    acc1 = __builtin_amdgcn_mfma_f32_16x16x32_bf16(a, b1, acc1, 0, 0, 0);
    acc2 = __builtin_amdgcn_mfma_f32_16x16x32_bf16(a, b2, acc2, 0, 0, 0);
    acc3 = __builtin_amdgcn_mfma_f32_16x16x32_bf16(a, b3, acc3, 0, 0, 0);
  }
  int row0 = m0 + (lane >> 4)*4, col = lane & 15;
  #pragma unroll
  for (int s = 0; s < 4; s++) {
    f32x4 acc = (s==0) ? acc0 : (s==1) ? acc1 : (s==2) ? acc2 : acc3;
    int n = n0 + s*16 + col;
    float bb = bias[n];
    #pragma unroll
    for (int rr = 0; rr < 4; rr++)
      C[(size_t)(row0+rr)*N2 + n] = f2bf(acc[rr] + bb);
  }
}

// ---------------- classifier GEMM: logits[m][l] (N padded to 16, fp32 out) ----------------
__global__ __launch_bounds__(256) void k_cls(const unsigned short* __restrict__ X,
    const unsigned short* __restrict__ Wb, const float* __restrict__ cb,
    float* __restrict__ out) {
  int lane = threadIdx.x & 63, wave = threadIdx.x >> 6;
  int m0 = blockIdx.x*64 + wave*16;
  int r = lane & 15, kg = lane >> 4;
  const short8* Ap = (const short8*)(X  + (size_t)(m0 + r)*512 + kg*8);
  const short8* Bp = (const short8*)(Wb + (size_t)r*512 + kg*8);
  f32x4 acc = {0,0,0,0};
  #pragma unroll
  for (int kb = 0; kb < 16; kb++)
    acc = __builtin_amdgcn_mfma_f32_16x16x32_bf16(Ap[kb*4], Bp[kb*4], acc, 0, 0, 0);
  int row0 = m0 + (lane >> 4)*4, col = lane & 15;
  if (col < NL_) {
    float bb = cb[col];
    #pragma unroll
    for (int rr = 0; rr < 4; rr++)
      out[(size_t)(row0+rr)*NL_ + col] = acc[rr] + bb;
  }
}

// ---------------- LSTM recurrence ----------------
// R6 = R5 structure with the asm pinning made legal: clang rejects "+v" on
// uint4 (tied INDIRECT register inputs); "+v" on scalar u32 is a direct
// register and is supported. 96 scalars, 4 asm statements (30-operand limit).
// Rationale (R1-R4 evidence): the max-occupancy scheduler rematerializes
// loop-invariant weight loads to hit 2 blocks/CU (R4: VGPR=64, SGPR=32, no
// scratch => pure L2 re-read; 393KB/step ~= measured 6270 cyc/step). The tied
// asm makes iter N+1 consume iter N's asm OUTPUT -> remat from memory illegal.

// DD: one fdot2, h-pair broadcast via v_readlane -> SGPR (the one SGPR
// operand VOP3P allows). 1 readlane : 1 fdot2.
#define DD(W, HV, LN, ACC) { unsigned int s_ = (unsigned int)__builtin_amdgcn_readlane((int)(HV), (LN)); ACC = fdot2((W), s_, ACC); }

// R4G: 4 consecutive pairs vs lanes B0..B0+3 of HV; alternate a0/p0 chains.
#define R4G(HV, B0, WA, WB, WC, WD) \
  DD(WA, HV, (B0)+0, a0) DD(WB, HV, (B0)+1, p0) DD(WC, HV, (B0)+2, a0) DD(WD, HV, (B0)+3, p0)

// LCH: one LDS-weight uint4 = pairs 96+P..96+P+3, h from hv3 lanes P..P+3.
#define LCH(Q, P) do { \
  DD((Q).x, hv3, (P)+0, a0) DD((Q).y, hv3, (P)+1, p0) \
  DD((Q).z, hv3, (P)+2, a0) DD((Q).w, hv3, (P)+3, p0) \
} while(0)

__global__ __launch_bounds__(1024, 4)
void k_rec(const unsigned short* __restrict__ xp,
    const unsigned int* __restrict__ wreg, const unsigned int* __restrict__ wlds,
    unsigned short* __restrict__ xout, int layer) {
  extern __shared__ char smem[];
  unsigned int* wl    = (unsigned int*)smem;                     // 32768 uints = 128KB
  float*        gates = (float*)(smem + 131072);                 // 1024 f32
  unsigned int* hpair = (unsigned int*)(smem + 131072 + 4096);   // 128 uints (256 fp16)
  int t = threadIdx.x;
  int b = blockIdx.x >> 1, d = blockIdx.x & 1;
  int ld = layer*2 + d;
  {
    const uint4* src = (const uint4*)(wlds + (size_t)ld*32768);
    uint4* dst = (uint4*)wl;
    #pragma unroll
    for (int i = 0; i < 8; i++) dst[t + i*1024] = src[t + i*1024];
  }
  // 96 weight pairs of column t as SCALAR SSA values (96 VGPR), via 24 dwordx4.
  const uint4* wp4 = (const uint4*)(wreg + ((size_t)ld*1024 + t)*96);
  uint4 T0  = wp4[ 0]; unsigned int w0 =T0.x,  w1 =T0.y,  w2 =T0.z,  w3 =T0.w;
  uint4 T1  = wp4[ 1]; unsigned int w4 =T1.x,  w5 =T1.y,  w6 =T1.z,  w7 =T1.w;
  uint4 T2  = wp4[ 2]; unsigned int w8 =T2.x,  w9 =T2.y,  w10=T2.z,  w11=T2.w;
  uint4 T3  = wp4[ 3]; unsigned int w12=T3.x,  w13=T3.y,  w14=T3.z,  w15=T3.w;
  uint4 T4  = wp4[ 4]; unsigned int w16=T4.x,  w17=T4.y,  w18=T4.z,  w19=T4.w;
  uint4 T5  = wp4[ 5]; unsigned int w20=T5.x,  w21=T5.y,  w22=T5.z,  w23=T5.w;
  uint4 T6  = wp4[ 6]; unsigned int w24=T6.x,  w25=T6.y,  w26=T6.z,  w27=T6.w;
  uint4 T7  = wp4[ 7]; unsigned int w28=T7.x,  w29=T7.y,  w30=T7.z,  w31=T7.w;
  uint4 T8  = wp4[ 8]; unsigned int w32=T8.x,  w33=T8.y,  w34=T8.z,  w35=T8.w;
  uint4 T9  = wp4[ 9]; unsigned int w36=T9.x,  w37=T9.y,  w38=T9.z,  w39=T9.w;
  uint4 T10 = wp4[10]; unsigned int w40=T10.x, w41=T10.y, w42=T10.z, w43=T10.w;
  uint4 T11 = wp4[11]; unsigned int w44=T11.x, w45=T11.y, w46=T11.z, w47=T11.w;
  uint4 T12 = wp4[12]; unsigned int w48=T12.x, w49=T12.y, w50=T12.z, w51=T12.w;
  uint4 T13 = wp4[13]; unsigned int w52=T13.x, w53=T13.y, w54=T13.z, w55=T13.w;
  uint4 T14 = wp4[14]; unsigned int w56=T14.x, w57=T14.y, w58=T14.z, w59=T14.w;
  uint4 T15 = wp4[15]; unsigned int w60=T15.x, w61=T15.y, w62=T15.z, w63=T15.w;
  uint4 T16 = wp4[16]; unsigned int w64=T16.x, w65=T16.y, w66=T16.z, w67=T16.w;
  uint4 T17 = wp4[17]; unsigned int w68=T17.x, w69=T17.y, w70=T17.z, w71=T17.w;
  uint4 T18 = wp4[18]; unsigned int w72=T18.x, w73=T18.y, w74=T18.z, w75=T18.w;
  uint4 T19 = wp4[19]; unsigned int w76=T19.x, w77=T19.y, w78=T19.z, w79=T19.w;
  uint4 T20 = wp4[20]; unsigned int w80=T20.x, w81=T20.y, w82=T20.z, w83=T20.w;
  uint4 T21 = wp4[21]; unsigned int w84=T21.x, w85=T21.y, w86=T21.z, w87=T21.w;
  uint4 T22 = wp4[22]; unsigned int w88=T22.x, w89=T22.y, w90=T22.z, w91=T22.w;
  uint4 T23 = wp4[23]; unsigned int w92=T23.x, w93=T23.y, w94=T23.z, w95=T23.w;
  if (t < 128) hpair[t] = 0u;
  float cst = 0.f;
  const unsigned short* xbase = xp + (size_t)b*T_*N2 + (size_t)d*G4;
  unsigned short* obase = xout + (size_t)b*T_*HID_ + d*H_;
  __syncthreads();
  int tt = d ? (T_-1) : 0;
  int l31 = t & 31;
  const uint4* wl4 = (const uint4*)wl;
  float nxt = bf2f(xbase[(size_t)tt*N2 + t]);
  #pragma unroll 1
  for (int step = 0; step < T_; step++) {
    // Pin all 96 weight scalars: remat from memory is now illegal.
    asm volatile("" : "+v"(w0), "+v"(w1), "+v"(w2), "+v"(w3), "+v"(w4), "+v"(w5),
                      "+v"(w6), "+v"(w7), "+v"(w8), "+v"(w9), "+v"(w10),"+v"(w11),
                      "+v"(w12),"+v"(w13),"+v"(w14),"+v"(w15),"+v"(w16),"+v"(w17),
                      "+v"(w18),"+v"(w19),"+v"(w20),"+v"(w21),"+v"(w22),"+v"(w23));
    asm volatile("" : "+v"(w24),"+v"(w25),"+v"(w26),"+v"(w27),"+v"(w28),"+v"(w29),
                      "+v"(w30),"+v"(w31),"+v"(w32),"+v"(w33),"+v"(w34),"+v"(w35),
                      "+v"(w36),"+v"(w37),"+v"(w38),"+v"(w39),"+v"(w40),"+v"(w41),
                      "+v"(w42),"+v"(w43),"+v"(w44),"+v"(w45),"+v"(w46),"+v"(w47));
    asm volatile("" : "+v"(w48),"+v"(w49),"+v"(w50),"+v"(w51),"+v"(w52),"+v"(w53),
                      "+v"(w54),"+v"(w55),"+v"(w56),"+v"(w57),"+v"(w58),"+v"(w59),
                      "+v"(w60),"+v"(w61),"+v"(w62),"+v"(w63),"+v"(w64),"+v"(w65),
                      "+v"(w66),"+v"(w67),"+v"(w68),"+v"(w69),"+v"(w70),"+v"(w71));
    asm volatile("" : "+v"(w72),"+v"(w73),"+v"(w74),"+v"(w75),"+v"(w76),"+v"(w77),
                      "+v"(w78),"+v"(w79),"+v"(w80),"+v"(w81),"+v"(w82),"+v"(w83),
                      "+v"(w84),"+v"(w85),"+v"(w86),"+v"(w87),"+v"(w88),"+v"(w89),
                      "+v"(w90),"+v"(w91),"+v"(w92),"+v"(w93),"+v"(w94),"+v"(w95));
    float a0 = nxt, p0 = 0.f;
    int ttn = d ? (T_-2-step) : (step+1);
    if (step < T_-1) nxt = bf2f(xbase[(size_t)ttn*N2 + t]);   // prefetch next x-projection
    unsigned int hv0 = hpair[l31];
    unsigned int hv1 = hpair[32 + l31];
    unsigned int hv2 = hpair[64 + l31];
    unsigned int hv3 = hpair[96 + l31];
    R4G(hv0,  0, w0, w1, w2, w3)   R4G(hv0,  4, w4, w5, w6, w7)
    R4G(hv0,  8, w8, w9, w10,w11)  R4G(hv0, 12, w12,w13,w14,w15)
    R4G(hv0, 16, w16,w17,w18,w19)  R4G(hv0, 20, w20,w21,w22,w23)
    R4G(hv0, 24, w24,w25,w26,w27)  R4G(hv0, 28, w28,w29,w30,w31)
    R4G(hv1,  0, w32,w33,w34,w35)  R4G(hv1,  4, w36,w37,w38,w39)
    R4G(hv1,  8, w40,w41,w42,w43)  R4G(hv1, 12, w44,w45,w46,w47)
    R4G(hv1, 16, w48,w49,w50,w51)  R4G(hv1, 20, w52,w53,w54,w55)
    R4G(hv1, 24, w56,w57,w58,w59)  R4G(hv1, 28, w60,w61,w62,w63)
    R4G(hv2,  0, w64,w65,w66,w67)  R4G(hv2,  4, w68,w69,w70,w71)
    R4G(hv2,  8, w72,w73,w74,w75)  R4G(hv2, 12, w76,w77,w78,w79)
    R4G(hv2, 16, w80,w81,w82,w83)  R4G(hv2, 20, w84,w85,w86,w87)
    R4G(hv2, 24, w88,w89,w90,w91)  R4G(hv2, 28, w92,w93,w94,w95)
    {                                                         // pairs 96..127 (LDS weights)
      uint4 q0 = wl4[0*1024+t], q1 = wl4[1*1024+t];
      LCH(q0,  0); LCH(q1,  4);
      uint4 q2 = wl4[2*1024+t], q3 = wl4[3*1024+t];
      LCH(q2,  8); LCH(q3, 12);
      uint4 q4 = wl4[4*1024+t], q5 = wl4[5*1024+t];
      LCH(q4, 16); LCH(q5, 20);
      uint4 q6 = wl4[6*1024+t], q7 = wl4[7*1024+t];
      LCH(q6, 24); LCH(q7, 28);
    }
    gates[t] = a0 + p0;
    __syncthreads();
    if (t < H_) {
      float gi = sigm(gates[t]);
      float gf = sigm(gates[H_ + t]);
      float gg = tanhfast(gates[2*H_ + t]);
      float go = sigm(gates[3*H_ + t]);
      cst = gf*cst + gi*gg;
      float h = go * tanhfast(cst);
      ((_Float16*)hpair)[t] = (_Float16)h;
      obase[(size_t)tt*HID_ + t] = f2bf(h);
    }
    __syncthreads();
    tt = ttn;
  }
}

// ---------------- CRF ----------------
__global__ void k_zero(float* out) { if (threadIdx.x == 0) out[0] = 0.f; }

__global__ void k_crf(const float* __restrict__ logits, const int* __restrict__ labels,
                      const float* __restrict__ st, const float* __restrict__ et,
                      const float* __restrict__ tr, float* __restrict__ out) {
  int b = blockIdx.x, lane = threadIdx.x;
  bool act = lane < NL_;
  const float* lb = logits + (size_t)b*T_*NL_;
  float trc[9];
  #pragma unroll
  for (int i = 0; i < 9; i++) trc[i] = act ? tr[i*9 + lane] : 0.f;
  float em = act ? lb[lane] : -1e30f;
  float alpha = act ? (st[lane] + em) : -1e30f;
  int prev = labels[b*T_];
  float num = __shfl(alpha, prev);
  for (int ttt = 1; ttt < T_; ttt++) {
    em = act ? lb[ttt*NL_ + lane] : -1e30f;
    float vv[9]; float mx = -1e30f;
    #pragma unroll
    for (int i = 0; i < 9; i++) { vv[i] = __shfl(alpha, i) + trc[i]; mx = fmaxf(mx, vv[i]); }
    float s = 0.f;
    #pragma unroll
    for (int i = 0; i < 9; i++) s += __expf(vv[i] - mx);
    alpha = act ? (mx + __logf(s) + em) : -1e30f;
    int tag = labels[b*T_ + ttt];
    float emtag = __shfl(em, tag);
    if (lane == 0) num += tr[prev*9 + tag] + emtag;
    prev = tag;
  }
  float fa = act ? (alpha + et[lane]) : -1e30f;
  float mx = -1e30f;
  #pragma unroll
  for (int i = 0; i < 9; i++) mx = fmaxf(mx, __shfl(fa, i));
  float s = 0.f;
  #pragma unroll
  for (int i = 0; i < 9; i++) s += __expf(__shfl(fa, i) - mx);
  float denom = mx + __logf(s);
  if (lane == 0) {
    num += et[prev];
    atomicAdd(out, denom - num);
  }
}

// ---------------- launch ----------------
extern "C" void kernel_launch(void* const* d_in, const int* in_sizes, int n_in,
                              void* d_out, int out_size, void* d_ws, size_t ws_size,
                              hipStream_t stream) {
  const int*   ids    = (const int*)d_in[0];
  const int*   labels = (const int*)d_in[1];
  const float* emb    = (const float*)d_in[2];
  const float* w_ih   = (const float*)d_in[3];
  const float* w_hh   = (const float*)d_in[4];
  const float* b_ih   = (const float*)d_in[5];
  const float* b_hh   = (const float*)d_in[6];
  const float* cls_w  = (const float*)d_in[7];
  const float* cls_b  = (const float*)d_in[8];
  const float* st     = (const float*)d_in[9];
  const float* et     = (const float*)d_in[10];
  const float* tr     = (const float*)d_in[11];
  float* out = (float*)d_out;

  char* ws = (char*)d_ws;
  unsigned short* xp    = (unsigned short*)(ws);                  // 134,217,728
  unsigned short* x0    = (unsigned short*)(ws + 134217728);      //  33,554,432
  unsigned short* x1    = (unsigned short*)(ws + 167772160);      //  33,554,432
  unsigned short* wbi   = (unsigned short*)(ws + 201326592);      //   4,194,304
  unsigned int*   wreg  = (unsigned int*)  (ws + 205520896);      //   1,572,864
  unsigned int*   wldsg = (unsigned int*)  (ws + 207093760);      //     524,288
  float*          bsum  = (float*)         (ws + 207618048);      //      16,384
  unsigned short* clswb = (unsigned short*)(ws + 207634432);      //      16,384
  float*          logit = (float*)         (ws + 207650816);      //   1,179,648  (end ~199.1 MiB)

  const int REC_SMEM = 131072 + 4096 + 512;
  (void)hipFuncSetAttribute((const void*)k_rec, hipFuncAttributeMaxDynamicSharedMemorySize, REC_SMEM);

  k_cast_bf16<<<8192, 256, 0, stream>>>(w_ih, wbi, 2*N2*512);
  k_pack_whh <<<2048, 256, 0, stream>>>(w_hh, wreg, wldsg);
  k_bias_sum <<<16,   256, 0, stream>>>(b_ih, b_hh, bsum);
  k_cls_pad  <<<32,   256, 0, stream>>>(cls_w, clswb);
  k_embed    <<<16384,256, 0, stream>>>(ids, emb, x0);

  dim3 ggrid(32, 512);
  k_gemm_inproj<<<ggrid, 256, 0, stream>>>(x0, wbi, bsum, xp);
  k_rec<<<128, 1024, REC_SMEM, stream>>>(xp, wreg, wldsg, x1, 0);
  k_gemm_inproj<<<ggrid, 256, 0, stream>>>(x1, wbi + (size_t)N2*512, bsum + 2048, xp);
  k_rec<<<128, 1024, REC_SMEM, stream>>>(xp, wreg, wldsg, x0, 1);   // x2 reuses x0
  k_cls<<<512, 256, 0, stream>>>(x0, clswb, cls_b, logit);
  k_zero<<<1, 64, 0, stream>>>(out);
  k_crf<<<64, 64, 0, stream>>>(logit, labels, st, et, tr, out);
}